// Round 11
// baseline (250.166 us; speedup 1.0000x reference)
//
#include <hip/hip_runtime.h>
#include <math.h>

#define B_   2
#define N_   2048
#define DIM_ 512
#define NH_  8
#define HD_  64
#define K_   32
#define PD_  16
#define TOK_ (B_*N_)     // 4096 rows
#define FFN_ 2048
#define QKV_ (3*DIM_)    // 1536
#define KV_  1024        // k|v bf16 row length

typedef __bf16 bf16x8 __attribute__((ext_vector_type(8)));
typedef float  f32x4  __attribute__((ext_vector_type(4)));

__device__ __forceinline__ unsigned short f2bf(float f) {
    unsigned int u = __float_as_uint(f);
    u = (u + 0x7fffu + ((u >> 16) & 1u)) >> 16;
    return (unsigned short)u;
}

__device__ __forceinline__ float bflo(unsigned u) { return __uint_as_float(u << 16); }
__device__ __forceinline__ float bfhi(unsigned u) { return __uint_as_float(u & 0xffff0000u); }

__device__ __forceinline__ float gelu_tanh(float x) {
    float x3 = x * x * x;
    return 0.5f * x * (1.f + tanhf(0.7978845608028654f * (x + 0.044715f * x3)));
}

__device__ __forceinline__ float tanh_fast(float x) {
    float e = __expf(2.f * x);
    return 1.f - 2.f / (e + 1.f);
}

__device__ __forceinline__ int lane_mbcnt(unsigned long long m) {
    return __builtin_amdgcn_mbcnt_hi((unsigned)(m >> 32),
           __builtin_amdgcn_mbcnt_lo((unsigned)m, 0));
}

// async global->LDS, 16B per lane. LDS dst must be wave-uniform base + lane*16.
#define GLOAD_LDS16(g, l) __builtin_amdgcn_global_load_lds(                        \
    (const __attribute__((address_space(1))) unsigned int*)(const void*)(g),       \
    (__attribute__((address_space(3))) unsigned int*)(void*)(l), 16, 0, 0)

// ---------------------------------------------------------------------------
// vectorized LayerNorm of one 512-f32 row per wave: float4-pair load,
// shfl-reduce, packed 8xbf16 store (G13: scalar bf16 stores ~2x slower).
// ---------------------------------------------------------------------------
__device__ __forceinline__ void ln_row_vec(const float* __restrict__ xr,
                                           const float* __restrict__ scale,
                                           const float* __restrict__ bias,
                                           unsigned short* __restrict__ yr,
                                           int lane)
{
    const float4* xp = (const float4*)(xr + lane * 8);
    float4 a = xp[0], b = xp[1];
    float s = a.x + a.y + a.z + a.w + b.x + b.y + b.z + b.w;
#pragma unroll
    for (int off = 32; off; off >>= 1) s += __shfl_xor(s, off);
    float m = s * (1.f / DIM_);
    float vs = (a.x-m)*(a.x-m) + (a.y-m)*(a.y-m) + (a.z-m)*(a.z-m) + (a.w-m)*(a.w-m)
             + (b.x-m)*(b.x-m) + (b.y-m)*(b.y-m) + (b.z-m)*(b.z-m) + (b.w-m)*(b.w-m);
#pragma unroll
    for (int off = 32; off; off >>= 1) vs += __shfl_xor(vs, off);
    float inv = rsqrtf(vs * (1.f / DIM_) + 1e-6f);
    const float4* gp = (const float4*)(scale + lane * 8);
    const float4* ep = (const float4*)(bias  + lane * 8);
    float4 g0 = gp[0], g1 = gp[1], e0 = ep[0], e1 = ep[1];
    unsigned w0 = (unsigned)f2bf((a.x-m)*inv*g0.x + e0.x)
                | ((unsigned)f2bf((a.y-m)*inv*g0.y + e0.y) << 16);
    unsigned w1 = (unsigned)f2bf((a.z-m)*inv*g0.z + e0.z)
                | ((unsigned)f2bf((a.w-m)*inv*g0.w + e0.w) << 16);
    unsigned w2 = (unsigned)f2bf((b.x-m)*inv*g1.x + e1.x)
                | ((unsigned)f2bf((b.y-m)*inv*g1.y + e1.y) << 16);
    unsigned w3 = (unsigned)f2bf((b.z-m)*inv*g1.z + e1.z)
                | ((unsigned)f2bf((b.w-m)*inv*g1.w + e1.w) << 16);
    uint4 pk = {w0, w1, w2, w3};
    *(uint4*)(yr + lane * 8) = pk;
}

// ---------------------------------------------------------------------------
// GEMM block body: C[M,N] = A[M,Kd] @ Bt[N,Kd]^T, BK=64, 8-chunk XOR swizzle
// (0 bank conflicts, staging lane-ordered for global_load_lds). 256 thr,
// 4 waves 2x2.
// DBUF=true : double-buffered LDS — used standalone.
// DBUF=false: single buffer, half LDS — used in the fused kernel where
//             co-resident topk/transpose waves hide the staging latency.
// PRIO=true : s_setprio(1) around the MFMA cluster (T5). ONLY in the fused
//             kernel: role diversity (topk ballot-waves vs GEMM MFMA-waves
//             co-resident) is T5's prerequisite; lockstep standalone GEMMs
//             showed a slight negative (m190), so they keep it off.
// EPI: 0 +bias->fp32 ; 1 +bias+res->fp32 ; 2 gelu(+bias)->bf16
//      3 QKV split: col<512 -> q fp32; col>=512 -> kv bf16 [row][1024]
// ---------------------------------------------------------------------------
template<int EPI, int BM, int BN, bool DBUF, bool PRIO>
__device__ __forceinline__ void gemm_block(const unsigned short* __restrict__ A,
                      const unsigned short* __restrict__ Bt,
                      const float* __restrict__ bias,
                      const float* __restrict__ res,
                      float* __restrict__ Cf,
                      unsigned short* __restrict__ Cb,
                      int N, int Kd, int bm0, int bn0,
                      unsigned short* smem)
{
    constexpr int WM = BM / 2;
    constexpr int WN = BN / 2;
    constexpr int FM = WM / 16;
    constexpr int FN = WN / 16;
    constexpr int BUFSZ = (BM + BN) * 64;

    int t    = threadIdx.x;
    int lane = t & 63;
    int wid  = t >> 6;
    int wm   = wid >> 1, wn = wid & 1;
    int quad = lane >> 4;
    int rlo  = lane & 15;

    f32x4 acc[FM][FN] = {};

    auto stage = [&](int buf, int k0) {
        unsigned short* As_ = smem + buf * BUFSZ;
        unsigned short* Bs_ = As_ + BM * 64;
#pragma unroll
        for (int l = 0; l < BM/32; l++) {
            int idx = l*256 + t;
            int r   = idx >> 3;
            int g   = (idx & 7) ^ (r & 7);
            GLOAD_LDS16(A + (size_t)(bm0 + r) * Kd + k0 + g*8, As_ + idx*8);
        }
#pragma unroll
        for (int l = 0; l < BN/32; l++) {
            int idx = l*256 + t;
            int r   = idx >> 3;
            int g   = (idx & 7) ^ (r & 7);
            GLOAD_LDS16(Bt + (size_t)(bn0 + r) * Kd + k0 + g*8, Bs_ + idx*8);
        }
    };

    auto compute = [&](int buf) {
        unsigned short* As_ = smem + buf * BUFSZ;
        unsigned short* Bs_ = As_ + BM * 64;
        bf16x8 af[FM][2], bfr[FN][2];
#pragma unroll
        for (int mi = 0; mi < FM; mi++) {
            int r = wm*WM + mi*16 + rlo;
#pragma unroll
            for (int s = 0; s < 2; s++)
                af[mi][s] = *(const bf16x8*)(As_ + r*64 + ((s*4 + quad) ^ (r & 7))*8);
        }
#pragma unroll
        for (int ni = 0; ni < FN; ni++) {
            int r = wn*WN + ni*16 + rlo;
#pragma unroll
            for (int s = 0; s < 2; s++)
                bfr[ni][s] = *(const bf16x8*)(Bs_ + r*64 + ((s*4 + quad) ^ (r & 7))*8);
        }
        if (PRIO) __builtin_amdgcn_s_setprio(1);
#pragma unroll
        for (int s = 0; s < 2; s++)
#pragma unroll
            for (int mi = 0; mi < FM; mi++)
#pragma unroll
                for (int ni = 0; ni < FN; ni++)
                    acc[mi][ni] = __builtin_amdgcn_mfma_f32_16x16x32_bf16(
                        af[mi][s], bfr[ni][s], acc[mi][ni], 0, 0, 0);
        if (PRIO) __builtin_amdgcn_s_setprio(0);
    };

    if constexpr (DBUF) {
        stage(0, 0);
        int buf = 0;
        for (int k0 = 0; k0 < Kd; k0 += 64) {
            __syncthreads();                       // drains stage(cur); also fences
            if (k0 + 64 < Kd) stage(buf ^ 1, k0 + 64);   // prefetch next tile
            compute(buf);                          // overlap with prefetch in flight
            buf ^= 1;
        }
    } else {
        for (int k0 = 0; k0 < Kd; k0 += 64) {
            stage(0, k0);
            __syncthreads();                       // staging complete (vmcnt drain)
            compute(0);
            __syncthreads();                       // all reads done before re-stage
        }
    }

    // epilogue: D row = quad*4 + r, col = rlo within each 16x16 tile
#pragma unroll
    for (int mi = 0; mi < FM; mi++) {
#pragma unroll
        for (int ni = 0; ni < FN; ni++) {
            int col = bn0 + wn*WN + ni*16 + rlo;
            float bv = bias[col];
#pragma unroll
            for (int r = 0; r < 4; r++) {
                int row = bm0 + wm*WM + mi*16 + quad*4 + r;
                float val = acc[mi][ni][r] + bv;
                if (EPI == 1) val += res[(size_t)row * N + col];
                if (EPI == 2) {
                    val = gelu_tanh(val);
                    Cb[(size_t)row * N + col] = f2bf(val);
                } else if (EPI == 3) {
                    if (col < DIM_) Cf[(size_t)row * DIM_ + col] = val;
                    else            Cb[(size_t)row * KV_ + (col - DIM_)] = f2bf(val);
                } else {
                    Cf[(size_t)row * N + col] = val;
                }
            }
        }
    }
}

template<int EPI, int BM, int BN>
__global__ __launch_bounds__(256)
void gemm_bf16_kernel(const unsigned short* __restrict__ A,
                      const unsigned short* __restrict__ Bt,
                      const float* __restrict__ bias,
                      const float* __restrict__ res,
                      float* __restrict__ Cf,
                      unsigned short* __restrict__ Cb,
                      int N, int Kd)
{
    __shared__ __align__(16) unsigned short smem[2 * (BM + BN) * 64];
    gemm_block<EPI, BM, BN, true, false>(A, Bt, bias, res, Cf, Cb, N, Kd,
                                         blockIdx.y * BM, blockIdx.x * BN, smem);
}

// ---------------------------------------------------------------------------
// top-K extraction helper (NR regs = NR*64 values per wave partition):
// lt pass (order irrelevant; merge re-ranks) + eq pass in ascending-j order
// (exact jax.lax.top_k lower-index-first).
// ---------------------------------------------------------------------------
template<int NR>
__device__ __forceinline__ void extract_row(const unsigned* rb, unsigned T,
                                            int cnt_lt, int m,
                                            unsigned long long* crow,
                                            int part, int jbase, int lane)
{
    int ltpos = 0;
#pragma unroll
    for (int tt = 0; tt < NR; tt++) {
        bool is_lt = rb[tt] < T;
        unsigned long long mlt = __ballot(is_lt);
        int p = ltpos + lane_mbcnt(mlt);
        if (is_lt) {
            int j = jbase + (tt >> 2)*256 + lane*4 + (tt & 3);
            crow[part*K_ + p] = ((unsigned long long)rb[tt] << 32) | (unsigned)j;
        }
        ltpos += __popcll(mlt);
    }
    int eqpos = 0;
#pragma unroll
    for (int jg = 0; jg < NR/4; jg++) {
        bool iseq[4]; unsigned long long meq[4]; int bel[4];
#pragma unroll
        for (int jj = 0; jj < 4; jj++) {
            iseq[jj] = (rb[jg*4+jj] == T);
            meq[jj]  = __ballot(iseq[jj]);
            bel[jj]  = lane_mbcnt(meq[jj]);
        }
        int lane_prefix = bel[0] + bel[1] + bel[2] + bel[3];
        int within = 0;
#pragma unroll
        for (int jj = 0; jj < 4; jj++) {
            int p = eqpos + lane_prefix + within;
            if (iseq[jj] && p < m) {
                int j = jbase + jg*256 + lane*4 + jj;
                crow[part*K_ + cnt_lt + p] =
                    ((unsigned long long)rb[jg*4+jj] << 32) | (unsigned)j;
            }
            within += iseq[jj] ? 1 : 0;
        }
        eqpos += __popcll(meq[0]) + __popcll(meq[1]) + __popcll(meq[2]) + __popcll(meq[3]);
    }
}

// ---------------------------------------------------------------------------
// Poincare dist + exact top-K block body (R12 structure: 2 rows/block,
// 4 waves = j-quarters, 2-bit radix select with carried counts,
// 128-candidate merge).
// ---------------------------------------------------------------------------
__device__ __forceinline__ void topk_block(const float* __restrict__ pos,
                      const float* __restrict__ posT,
                      const float* __restrict__ pos_sq,
                      const float* __restrict__ c_ptr,
                      int* __restrict__ topk_idx, float* __restrict__ topk_dist,
                      int bi0, unsigned long long (*cand)[128])
{
    int wid  = threadIdx.x >> 6;      // j-quarter 0..3
    int lane = threadIdx.x & 63;
    int b    = bi0 >> 11;             // both rows of a block share the batch
    float c  = *c_ptr;
    float inv_sqrt_c = rsqrtf(c);

    float pi0[16], pi1[16];
    {
        const float4* q0 = (const float4*)(pos + (size_t)bi0 * PD_);
        const float4* q1 = (const float4*)(pos + (size_t)(bi0+1) * PD_);
#pragma unroll
        for (int u = 0; u < 4; u++) {
            float4 a = q0[u];
            pi0[4*u]=a.x; pi0[4*u+1]=a.y; pi0[4*u+2]=a.z; pi0[4*u+3]=a.w;
            float4 e = q1[u];
            pi1[4*u]=e.x; pi1[4*u+1]=e.y; pi1[4*u+2]=e.z; pi1[4*u+3]=e.w;
        }
    }
    float om0 = 1.f - c * pos_sq[bi0];
    float om1 = 1.f - c * pos_sq[bi0+1];

    const float* pT  = posT + (size_t)b * 16 * N_;
    const float* sqb = pos_sq + b * N_;
    int jbase = wid * 512;
    int j0l   = jbase + lane * 4;

    unsigned rb0[8], rb1[8];
#pragma unroll
    for (int jg = 0; jg < 2; jg++) {
        int j0 = j0l + jg * 256;
        float ax=0,ay=0,az=0,aw=0, bx=0,by=0,bz=0,bw=0;
#pragma unroll
        for (int d = 0; d < 16; d++) {
            float4 v = *(const float4*)(pT + d * N_ + j0);
            float d0x = pi0[d]-v.x, d0y = pi0[d]-v.y, d0z = pi0[d]-v.z, d0w = pi0[d]-v.w;
            ax += d0x*d0x; ay += d0y*d0y; az += d0z*d0z; aw += d0w*d0w;
            float d1x = pi1[d]-v.x, d1y = pi1[d]-v.y, d1z = pi1[d]-v.z, d1w = pi1[d]-v.w;
            bx += d1x*d1x; by += d1y*d1y; bz += d1z*d1z; bw += d1w*d1w;
        }
        float4 sq = *(const float4*)(sqb + j0);
        float da[4]={ax,ay,az,aw}, db[4]={bx,by,bz,bw}, sqa[4]={sq.x,sq.y,sq.z,sq.w};
#pragma unroll
        for (int jj = 0; jj < 4; jj++) {
            float omj  = 1.f - c * sqa[jj];
            float den0 = fmaxf(om0 * omj, 1e-8f);
            float den1 = fmaxf(om1 * omj, 1e-8f);
            rb0[jg*4+jj] = __float_as_uint(fmaxf(1.f + 2.f*c*da[jj]/den0, 1.f+1e-7f));
            rb1[jg*4+jj] = __float_as_uint(fmaxf(1.f + 2.f*c*db[jj]/den1, 1.f+1e-7f));
        }
    }

    // --- common-prefix skip + 2-bit radix select, counts carried ---
    unsigned T0, T1;
    int cl0 = 0, cl1 = 0;              // count(< T) — maintained on accept
    {
        unsigned band0 = rb0[0], bor0 = rb0[0], band1 = rb1[0], bor1 = rb1[0];
#pragma unroll
        for (int tt = 1; tt < 8; tt++) {
            band0 &= rb0[tt]; bor0 |= rb0[tt];
            band1 &= rb1[tt]; bor1 |= rb1[tt];
        }
#pragma unroll
        for (int off = 32; off; off >>= 1) {
            band0 &= __shfl_xor(band0, off); bor0 |= __shfl_xor(bor0, off);
            band1 &= __shfl_xor(band1, off); bor1 |= __shfl_xor(bor1, off);
        }
        unsigned df0 = band0 ^ bor0, df1 = band1 ^ bor1;
        int hib0 = df0 ? (31 - __clz(df0)) : -1;
        int hib1 = df1 ? (31 - __clz(df1)) : -1;
        int hib  = hib0 > hib1 ? hib0 : hib1;
        T0 = (hib >= 0) ? (band0 & ~((1u << (hib+1)) - 1u)) : band0;
        T1 = (hib >= 0) ? (band1 & ~((1u << (hib+1)) - 1u)) : band1;
        // count(< T_init) == 0: all values share T's prefix, T's low bits = 0
        int bit = hib;
        while (bit >= 1) {                 // bits (bit, bit-1) per step
            unsigned lo = 1u << (bit - 1);
            unsigned p01 = T0 | lo, p02 = T0 | (lo << 1), p03 = T0 | (lo*3u);
            unsigned p11 = T1 | lo, p12 = T1 | (lo << 1), p13 = T1 | (lo*3u);
            int c01=0,c02=0,c03=0,c11=0,c12=0,c13=0;
#pragma unroll
            for (int tt = 0; tt < 8; tt++) {
                c01 += __popcll(__ballot(rb0[tt] < p01));
                c02 += __popcll(__ballot(rb0[tt] < p02));
                c03 += __popcll(__ballot(rb0[tt] < p03));
                c11 += __popcll(__ballot(rb1[tt] < p11));
                c12 += __popcll(__ballot(rb1[tt] < p12));
                c13 += __popcll(__ballot(rb1[tt] < p13));
            }
            if      (c03 < K_) { T0 = p03; cl0 = c03; }
            else if (c02 < K_) { T0 = p02; cl0 = c02; }
            else if (c01 < K_) { T0 = p01; cl0 = c01; }
            if      (c13 < K_) { T1 = p13; cl1 = c13; }
            else if (c12 < K_) { T1 = p12; cl1 = c12; }
            else if (c11 < K_) { T1 = p11; cl1 = c11; }
            bit -= 2;
        }
        if (bit == 0) {                    // leftover single bit
            unsigned p0 = T0 | 1u, p1 = T1 | 1u;
            int c0 = 0, c1 = 0;
#pragma unroll
            for (int tt = 0; tt < 8; tt++) {
                c0 += __popcll(__ballot(rb0[tt] < p0));
                c1 += __popcll(__ballot(rb1[tt] < p1));
            }
            if (c0 < K_) { T0 = p0; cl0 = c0; }
            if (c1 < K_) { T1 = p1; cl1 = c1; }
        }
    }

    extract_row<8>(rb0, T0, cl0, K_ - cl0, cand[0], wid, jbase, lane);
    extract_row<8>(rb1, T1, cl1, K_ - cl1, cand[1], wid, jbase, lane);
    __syncthreads();

    // --- merge: 2 waves per row rank 128 candidates (4 quarters x K) ---
    {
        int row  = wid >> 1, half = wid & 1;
        unsigned long long mykey = cand[row][half*64 + lane];
        int rank = 0;
#pragma unroll 8
        for (int M = 0; M < 128; M++)
            rank += (cand[row][M] < mykey) ? 1 : 0;
        if (rank < K_) {
            int bi = bi0 + row;
            topk_idx [(size_t)bi * K_ + rank] = (int)(mykey & 0xffffffffu);
            topk_dist[(size_t)bi * K_ + rank] =
                acoshf(__uint_as_float((unsigned)(mykey >> 32))) * inv_sqrt_c;
        }
    }
}

// ---------------------------------------------------------------------------
// FUSED QKV-GEMM + dist/top-K + tail-weight transposes. Grid 5888 = 23*256:
// per group of 23 consecutive blockIdx — 6 GEMM (1536 = 24x64 tiles of
// 64x64) + 8 topk (2048, 2 rows each) + 9 transpose (2304 = Wo 256 /
// W1 1024 / W2 1024 tiles of 32x32). Branch-max VGPR 56, no spills (R17/R20).
// R23: GEMM branch sets setprio(1) around its MFMA cluster (T5) — role
// diversity here comes from heterogeneous co-resident blocks.
// ---------------------------------------------------------------------------
__global__ __launch_bounds__(256)
void qkv_topk_kernel(const unsigned short* __restrict__ xn,
                     const unsigned short* __restrict__ qkvWt,
                     const float* __restrict__ qkv_b,
                     float* __restrict__ qf,
                     unsigned short* __restrict__ kvb,
                     const float* __restrict__ pos,
                     const float* __restrict__ posT,
                     const float* __restrict__ pos_sq,
                     const float* __restrict__ c_ptr,
                     int* __restrict__ tk_i, float* __restrict__ tk_d,
                     const float* __restrict__ Wo, const float* __restrict__ W1,
                     const float* __restrict__ W2,
                     unsigned short* __restrict__ WoT,
                     unsigned short* __restrict__ W1T,
                     unsigned short* __restrict__ W2T)
{
    __shared__ __align__(16) unsigned short smem[(64 + 64) * 64];  // 16 KB

    int g = blockIdx.x;
    int grp = g / 23;
    int r   = g - grp * 23;
    if (r < 6) {
        int gb = grp * 6 + r;            // [0,1536)
        int bx = gb % 24, by = gb / 24;  // grid 24 x 64 of 64x64 tiles
        gemm_block<3, 64, 64, false, true>(xn, qkvWt, qkv_b, nullptr, qf, kvb,
                                           QKV_, DIM_, by * 64, bx * 64, smem);
    } else if (r < 14) {
        int tb = grp * 8 + (r - 6);      // [0,2048)
        topk_block(pos, posT, pos_sq, c_ptr, tk_i, tk_d, tb * 2,
                   (unsigned long long (*)[128])smem);
    } else {
        int tid = grp * 9 + (r - 14);    // [0,2304)
        const float* W; unsigned short* Wt; int Kd, Nw, nx, ti;
        if      (tid < 256)  { W = Wo; Wt = WoT; Kd = 512;  Nw = 512;  nx = 16; ti = tid; }
        else if (tid < 1280) { W = W1; Wt = W1T; Kd = 512;  Nw = 2048; nx = 64; ti = tid - 256; }
        else                 { W = W2; Wt = W2T; Kd = 2048; Nw = 512;  nx = 16; ti = tid - 1280; }
        float (*tile)[33] = (float (*)[33])smem;   // 32x33 f32 = 4224B < 16KB
        int t  = threadIdx.x;
        int n0 = (ti % nx) * 32, k0 = (ti / nx) * 32;
        int tx = t & 31, ty = t >> 5;
#pragma unroll
        for (int i = 0; i < 32; i += 8)
            tile[ty + i][tx] = W[(size_t)(k0 + ty + i) * Nw + n0 + tx];
        __syncthreads();
#pragma unroll
        for (int i = 0; i < 32; i += 8)
            Wt[(size_t)(n0 + ty + i) * Kd + k0 + tx] = f2bf(tile[tx][ty + i]);
    }
}

// ---------------------------------------------------------------------------
// FUSED prep (critical-path only): Wq/Wk/Wv transposes + bias3 pack +
// pos_sq/posT + LN1 (vectorized). (Wo/W1/W2 transposes live in
// qkv_topk_kernel since R20.)
// id: [0,768) qkv transposes ; [768,774) bias ; [774,790) pos ; [790,1814) LN1
// ---------------------------------------------------------------------------
__global__ void fused_prep_kernel(const float* __restrict__ Wq, const float* __restrict__ Wk,
                            const float* __restrict__ Wv,
                            const float* __restrict__ bq, const float* __restrict__ bk,
                            const float* __restrict__ bv,
                            unsigned short* __restrict__ qkvWt,
                            float* __restrict__ qkv_b,
                            const float* __restrict__ pos,
                            float* __restrict__ pos_sq,
                            float* __restrict__ posT,
                            const float* __restrict__ x,
                            const float* __restrict__ ln1_scale,
                            const float* __restrict__ ln1_bias,
                            unsigned short* __restrict__ xn)
{
    int id = blockIdx.x;
    int t  = threadIdx.x;

    if (id >= 790) {                  // LN1 (vectorized)
        int wave = (id - 790) * 4 + (t >> 6);
        int lane = t & 63;
        ln_row_vec(x + (size_t)wave * DIM_, ln1_scale, ln1_bias,
                   xn + (size_t)wave * DIM_, lane);
        return;
    }
    if (id >= 774) {                  // pos_sq + posT
        int i = (id - 774) * 256 + t;
        int b = i >> 11, j = i & (N_ - 1);
        const float4* p = (const float4*)(pos + (size_t)i * PD_);
        float4 a0 = p[0], a1 = p[1], a2 = p[2], a3 = p[3];
        float pv[16] = {a0.x,a0.y,a0.z,a0.w, a1.x,a1.y,a1.z,a1.w,
                        a2.x,a2.y,a2.z,a2.w, a3.x,a3.y,a3.z,a3.w};
        float s = 0.f;
#pragma unroll
        for (int d = 0; d < 16; d++) s += pv[d]*pv[d];
        pos_sq[i] = s;
        float* pT = posT + (size_t)b * 16 * N_;
#pragma unroll
        for (int d = 0; d < 16; d++) pT[d * N_ + j] = pv[d];
        return;
    }
    if (id >= 768) {                  // bias pack
        int i = (id - 768) * 256 + t;
        if (i < DIM_)            qkv_b[i] = bq[i];
        else if (i < 2*DIM_)     qkv_b[i] = bk[i - DIM_];
        else                     qkv_b[i] = bv[i - 2*DIM_];
        return;
    }

    const float* W; unsigned short* Wt; int ti;
    if      (id < 256)  { W = Wq; Wt = qkvWt;             ti = id; }
    else if (id < 512)  { W = Wk; Wt = qkvWt + 512*512;   ti = id - 256; }
    else                { W = Wv; Wt = qkvWt + 2*512*512; ti = id - 512; }

    __shared__ float tile[32][33];
    int n0 = (ti % 16) * 32, k0 = (ti / 16) * 32;
    int tx = t & 31, ty = t >> 5;
#pragma unroll
    for (int i = 0; i < 32; i += 8)
        tile[ty + i][tx] = W[(size_t)(k0 + ty + i) * 512 + n0 + tx];
    __syncthreads();
#pragma unroll
    for (int i = 0; i < 32; i += 8)
        Wt[(size_t)(n0 + ty + i) * 512 + k0 + tx] = f2bf(tile[tx][ty + i]);
}

// ---------------------------------------------------------------------------
// LayerNorm standalone (LN2) — vectorized
// ---------------------------------------------------------------------------
__global__ void layernorm_kernel(const float* __restrict__ x,
                                 const float* __restrict__ scale,
                                 const float* __restrict__ bias,
                                 unsigned short* __restrict__ y)
{
    int wave = (blockIdx.x * blockDim.x + threadIdx.x) >> 6;
    int lane = threadIdx.x & 63;
    if (wave >= TOK_) return;
    ln_row_vec(x + (size_t)wave * DIM_, scale, bias,
               y + (size_t)wave * DIM_, lane);
}

// ---------------------------------------------------------------------------
// Sparse attention with bf16 K/V. One wave per (b,h,i).
// ---------------------------------------------------------------------------
__global__ __launch_bounds__(256)
void attn_kernel(const float* __restrict__ q,
                 const unsigned short* __restrict__ kv,
                 const int* __restrict__ topk_idx, const float* __restrict__ topk_dist,
                 const float* __restrict__ log_tau_p, const float* __restrict__ attn_scale_p,
                 unsigned int* __restrict__ out)   // bf16 pairs
{
    int gw   = (blockIdx.x * blockDim.x + threadIdx.x) >> 6;
    int lane = threadIdx.x & 63;
    if (gw >= B_ * NH_ * N_) return;
    int b = gw / (NH_ * N_);
    int r = gw % (NH_ * N_);
    int h = r / N_;
    int i = r % N_;
    int tok = b * N_ + i;

    float tau    = fmaxf(__expf(*log_tau_p), 1e-8f);
    float ascale = *attn_scale_p;

    const int*   idxp = topk_idx  + (size_t)tok * K_;
    const float* dstp = topk_dist + (size_t)tok * K_;
    int   my_idx  = idxp[lane & 31];
    float my_dist = dstp[lane & 31];

    int jj   = lane >> 1;
    int half = lane & 1;

    // q half: 32 floats
    const float4* qp = (const float4*)(q + (size_t)tok * DIM_ + h * HD_ + half * 32);
    float4 qv[8];
#pragma unroll
    for (int u = 0; u < 8; u++) qv[u] = qp[u];

    // k half (bf16): 32 shorts = 4 x 16B
    int nb = __shfl(my_idx, jj);
    const uint4* kp = (const uint4*)(kv + (size_t)(b * N_ + nb) * KV_ + h * HD_ + half * 32);
    float dot = 0.f;
#pragma unroll
    for (int u = 0; u < 4; u++) {
        uint4 kw = kp[u];
        dot += qv[2*u].x   * bflo(kw.x) + qv[2*u].y   * bfhi(kw.x)
             + qv[2*u].z   * bflo(kw.y) + qv[2*u].w   * bfhi(kw.y)
             + qv[2*u+1].x * bflo(kw.z) + qv[2*u+1].y * bfhi(kw.z)
             + qv[2*u+1].z * bflo(kw.w) + qv[2*u+1].w * bfhi(kw.w);
    }
    dot += __shfl_xor(dot, 1);   // full dot on both lanes of the pair

    float fs = dot * 0.125f;                        // 1/sqrt(64)
    float gs = -__shfl(my_dist, jj) / tau;
    float s  = ascale * tanh_fast(fs + gs);

    // softmax over the 32 scores (each duplicated on a lane pair)
    float mx = s;
#pragma unroll
    for (int off = 32; off; off >>= 1) mx = fmaxf(mx, __shfl_xor(mx, off));
    float e  = __expf(s - mx);
    float ec = half ? 0.f : e;
#pragma unroll
    for (int off = 32; off; off >>= 1) ec += __shfl_xor(ec, off);
    float inv = 1.f / ec;

    // V phase: dim pair d2 = 2*(lane&31); lane>=32 handles odd neighbors
    int dp    = lane & 31;
    int half2 = lane >> 5;
    const unsigned int* vb = (const unsigned int*)(kv + DIM_ + h * HD_) + dp;
    float ax = 0.f, ay = 0.f;
#pragma unroll
    for (int it = 0; it < 16; it++) {
        int t2 = half2 + 2*it;
        float w  = __shfl(e, t2 * 2) * inv;
        int   nj = __shfl(my_idx, t2);
        unsigned vv = vb[(size_t)(b * N_ + nj) * (KV_/2)];
        ax += w * bflo(vv);
        ay += w * bfhi(vv);
    }
    ax += __shfl_xor(ax, 32);
    ay += __shfl_xor(ay, 32);
    if (lane < 32) {
        unsigned pck = ((unsigned)f2bf(ay) << 16) | (unsigned)f2bf(ax);
        out[(size_t)tok * (DIM_/2) + h * (HD_/2) + dp] = pck;
    }
}

// ---------------------------------------------------------------------------
extern "C" void kernel_launch(void* const* d_in, const int* in_sizes, int n_in,
                              void* d_out, int out_size, void* d_ws, size_t ws_size,
                              hipStream_t stream)
{
    const float* x          = (const float*)d_in[0];
    const float* positions  = (const float*)d_in[1];
    const float* c_p        = (const float*)d_in[2];
    const float* Wq         = (const float*)d_in[3];
    const float* bq         = (const float*)d_in[4];
    const float* Wk         = (const float*)d_in[5];
    const float* bk         = (const float*)d_in[6];
    const float* Wv         = (const float*)d_in[7];
    const float* bv         = (const float*)d_in[8];
    const float* Wo         = (const float*)d_in[9];
    const float* bo         = (const float*)d_in[10];
    const float* W1         = (const float*)d_in[11];
    const float* b1         = (const float*)d_in[12];
    const float* W2         = (const float*)d_in[13];
    const float* b2         = (const float*)d_in[14];
    const float* ln1_scale  = (const float*)d_in[15];
    const float* ln1_bias   = (const float*)d_in[16];
    const float* ln2_scale  = (const float*)d_in[17];
    const float* ln2_bias   = (const float*)d_in[18];
    const float* log_tau    = (const float*)d_in[19];
    const float* attn_scale = (const float*)d_in[20];

    char* p = (char*)d_ws;
    unsigned short* qkvWt  = (unsigned short*)p; p += (size_t)QKV_ * DIM_ * 2;   // [1536][512] bf16
    unsigned short* WoT    = (unsigned short*)p; p += (size_t)DIM_ * DIM_ * 2;   // [512][512]
    unsigned short* W1T    = (unsigned short*)p; p += (size_t)FFN_ * DIM_ * 2;   // [2048][512]
    unsigned short* W2T    = (unsigned short*)p; p += (size_t)DIM_ * FFN_ * 2;   // [512][2048]
    float*          qkv_b  = (float*)p;          p += (size_t)QKV_ * 4;
    unsigned short* xn     = (unsigned short*)p; p += (size_t)TOK_ * DIM_ * 2;   // bf16
    float*          qf     = (float*)p;          p += (size_t)TOK_ * DIM_ * 4;   // fp32 q
    unsigned short* kvb    = (unsigned short*)p; p += (size_t)TOK_ * KV_ * 2;    // bf16 k|v
    unsigned short* attn_o = (unsigned short*)p; p += (size_t)TOK_ * DIM_ * 2;   // bf16
    float*          x1     = (float*)p;          p += (size_t)TOK_ * DIM_ * 4;
    unsigned short* x2n    = (unsigned short*)p; p += (size_t)TOK_ * DIM_ * 2;
    unsigned short* hbuf   = (unsigned short*)p; p += (size_t)TOK_ * FFN_ * 2;
    float*          pos_sq = (float*)p;          p += (size_t)TOK_ * 4;
    float*          posT   = (float*)p;          p += (size_t)B_ * 16 * N_ * 4;
    float*          tk_d   = (float*)p;          p += (size_t)TOK_ * K_ * 4;
    int*            tk_i   = (int*)p;            p += (size_t)TOK_ * K_ * 4;

    // --- prep (critical path only): qkv transposes + bias + pos + LN1 ---
    fused_prep_kernel<<<1814, 256, 0, stream>>>(Wq, Wk, Wv, bq, bk, bv,
                                                qkvWt, qkv_b,
                                                positions, pos_sq, posT,
                                                x, ln1_scale, ln1_bias, xn);

    // --- FUSED: QKV GEMM (1536) + dist/top-k (2048) + Wo/W1/W2 transposes
    //     (2304), 6:8:9 interleave over 5888 = 23*256 blocks ---
    qkv_topk_kernel<<<5888, 256, 0, stream>>>(xn, qkvWt, qkv_b, qf, kvb,
                                              positions, posT, pos_sq, c_p,
                                              tk_i, tk_d,
                                              Wo, W1, W2, WoT, W1T, W2T);

    // --- sparse attention -> bf16 ---
    attn_kernel<<<(B_*NH_*N_)/4, 256, 0, stream>>>(qf, kvb, tk_i, tk_d,
                                                   log_tau, attn_scale,
                                                   (unsigned int*)attn_o);

    // --- x1 = x + attn_o @ Wo + bo (fp32), 64x64 -> 512 blocks, dbuf ---
    gemm_bf16_kernel<1,64,64><<<dim3(DIM_/64, TOK_/64), 256, 0, stream>>>(
        attn_o, WoT, bo, x, x1, nullptr, DIM_, DIM_);

    // --- LN2 -> bf16 (vectorized) ---
    layernorm_kernel<<<TOK_/4, 256, 0, stream>>>(x1, ln2_scale, ln2_bias, x2n);

    // --- FFN1: gelu(x2n @ W1 + b1) -> bf16 h, 128x128 -> 512 blocks, dbuf ---
    gemm_bf16_kernel<2,128,128><<<dim3(FFN_/128, TOK_/128), 256, 0, stream>>>(
        x2n, W1T, b1, nullptr, nullptr, hbuf, FFN_, DIM_);

    // --- FFN2: out = x1 + h @ W2 + b2 (fp32), 64x128 -> 256 blocks, dbuf
    //     (R23: K=2048 makes FFN2 the largest tail GEMM; 64x128 raises
    //      per-FLOP rate ~1.5-1.7x per the measured tile ladder) ---
    gemm_bf16_kernel<1,64,128><<<dim3(DIM_/128, TOK_/64), 256, 0, stream>>>(
        hbuf, W2T, b2, x1, (float*)d_out, nullptr, DIM_, FFN_);
}

// Round 12
// 241.832 us; speedup vs baseline: 1.0345x; 1.0345x over previous
//
#include <hip/hip_runtime.h>
#include <math.h>

#define B_   2
#define N_   2048
#define DIM_ 512
#define NH_  8
#define HD_  64
#define K_   32
#define PD_  16
#define TOK_ (B_*N_)     // 4096 rows
#define FFN_ 2048
#define QKV_ (3*DIM_)    // 1536
#define KV_  1024        // k|v bf16 row length

typedef __bf16 bf16x8 __attribute__((ext_vector_type(8)));
typedef float  f32x4  __attribute__((ext_vector_type(4)));

__device__ __forceinline__ unsigned short f2bf(float f) {
    unsigned int u = __float_as_uint(f);
    u = (u + 0x7fffu + ((u >> 16) & 1u)) >> 16;
    return (unsigned short)u;
}

__device__ __forceinline__ float bflo(unsigned u) { return __uint_as_float(u << 16); }
__device__ __forceinline__ float bfhi(unsigned u) { return __uint_as_float(u & 0xffff0000u); }

__device__ __forceinline__ float gelu_tanh(float x) {
    float x3 = x * x * x;
    return 0.5f * x * (1.f + tanhf(0.7978845608028654f * (x + 0.044715f * x3)));
}

__device__ __forceinline__ float tanh_fast(float x) {
    float e = __expf(2.f * x);
    return 1.f - 2.f / (e + 1.f);
}

__device__ __forceinline__ int lane_mbcnt(unsigned long long m) {
    return __builtin_amdgcn_mbcnt_hi((unsigned)(m >> 32),
           __builtin_amdgcn_mbcnt_lo((unsigned)m, 0));
}

// async global->LDS, 16B per lane. LDS dst must be wave-uniform base + lane*16.
#define GLOAD_LDS16(g, l) __builtin_amdgcn_global_load_lds(                        \
    (const __attribute__((address_space(1))) unsigned int*)(const void*)(g),       \
    (__attribute__((address_space(3))) unsigned int*)(void*)(l), 16, 0, 0)

// ---------------------------------------------------------------------------
// vectorized LayerNorm of one 512-f32 row per wave: float4-pair load,
// shfl-reduce, packed 8xbf16 store (G13: scalar bf16 stores ~2x slower).
// ---------------------------------------------------------------------------
__device__ __forceinline__ void ln_row_vec(const float* __restrict__ xr,
                                           const float* __restrict__ scale,
                                           const float* __restrict__ bias,
                                           unsigned short* __restrict__ yr,
                                           int lane)
{
    const float4* xp = (const float4*)(xr + lane * 8);
    float4 a = xp[0], b = xp[1];
    float s = a.x + a.y + a.z + a.w + b.x + b.y + b.z + b.w;
#pragma unroll
    for (int off = 32; off; off >>= 1) s += __shfl_xor(s, off);
    float m = s * (1.f / DIM_);
    float vs = (a.x-m)*(a.x-m) + (a.y-m)*(a.y-m) + (a.z-m)*(a.z-m) + (a.w-m)*(a.w-m)
             + (b.x-m)*(b.x-m) + (b.y-m)*(b.y-m) + (b.z-m)*(b.z-m) + (b.w-m)*(b.w-m);
#pragma unroll
    for (int off = 32; off; off >>= 1) vs += __shfl_xor(vs, off);
    float inv = rsqrtf(vs * (1.f / DIM_) + 1e-6f);
    const float4* gp = (const float4*)(scale + lane * 8);
    const float4* ep = (const float4*)(bias  + lane * 8);
    float4 g0 = gp[0], g1 = gp[1], e0 = ep[0], e1 = ep[1];
    unsigned w0 = (unsigned)f2bf((a.x-m)*inv*g0.x + e0.x)
                | ((unsigned)f2bf((a.y-m)*inv*g0.y + e0.y) << 16);
    unsigned w1 = (unsigned)f2bf((a.z-m)*inv*g0.z + e0.z)
                | ((unsigned)f2bf((a.w-m)*inv*g0.w + e0.w) << 16);
    unsigned w2 = (unsigned)f2bf((b.x-m)*inv*g1.x + e1.x)
                | ((unsigned)f2bf((b.y-m)*inv*g1.y + e1.y) << 16);
    unsigned w3 = (unsigned)f2bf((b.z-m)*inv*g1.z + e1.z)
                | ((unsigned)f2bf((b.w-m)*inv*g1.w + e1.w) << 16);
    uint4 pk = {w0, w1, w2, w3};
    *(uint4*)(yr + lane * 8) = pk;
}

// ---------------------------------------------------------------------------
// GEMM block body: C[M,N] = A[M,Kd] @ Bt[N,Kd]^T, BK=64, 8-chunk XOR swizzle
// (0 bank conflicts, staging lane-ordered for global_load_lds). 256 thr,
// 4 waves 2x2.
// DBUF=true : double-buffered LDS — used standalone.
// DBUF=false: single buffer, half LDS — used in the fused kernel where
//             co-resident topk/transpose waves hide the staging latency.
// PRIO=true : s_setprio(1) around the MFMA cluster (T5). ONLY in the fused
//             kernel: role diversity (topk ballot-waves vs GEMM MFMA-waves
//             co-resident) is T5's prerequisite; lockstep standalone GEMMs
//             showed a slight negative (m190), so they keep it off.
// EPI: 0 +bias->fp32 ; 1 +bias+res->fp32 ; 2 gelu(+bias)->bf16
//      3 QKV split: col<512 -> q fp32; col>=512 -> kv bf16 [row][1024]
// ---------------------------------------------------------------------------
template<int EPI, int BM, int BN, bool DBUF, bool PRIO>
__device__ __forceinline__ void gemm_block(const unsigned short* __restrict__ A,
                      const unsigned short* __restrict__ Bt,
                      const float* __restrict__ bias,
                      const float* __restrict__ res,
                      float* __restrict__ Cf,
                      unsigned short* __restrict__ Cb,
                      int N, int Kd, int bm0, int bn0,
                      unsigned short* smem)
{
    constexpr int WM = BM / 2;
    constexpr int WN = BN / 2;
    constexpr int FM = WM / 16;
    constexpr int FN = WN / 16;
    constexpr int BUFSZ = (BM + BN) * 64;

    int t    = threadIdx.x;
    int lane = t & 63;
    int wid  = t >> 6;
    int wm   = wid >> 1, wn = wid & 1;
    int quad = lane >> 4;
    int rlo  = lane & 15;

    f32x4 acc[FM][FN] = {};

    auto stage = [&](int buf, int k0) {
        unsigned short* As_ = smem + buf * BUFSZ;
        unsigned short* Bs_ = As_ + BM * 64;
#pragma unroll
        for (int l = 0; l < BM/32; l++) {
            int idx = l*256 + t;
            int r   = idx >> 3;
            int g   = (idx & 7) ^ (r & 7);
            GLOAD_LDS16(A + (size_t)(bm0 + r) * Kd + k0 + g*8, As_ + idx*8);
        }
#pragma unroll
        for (int l = 0; l < BN/32; l++) {
            int idx = l*256 + t;
            int r   = idx >> 3;
            int g   = (idx & 7) ^ (r & 7);
            GLOAD_LDS16(Bt + (size_t)(bn0 + r) * Kd + k0 + g*8, Bs_ + idx*8);
        }
    };

    auto compute = [&](int buf) {
        unsigned short* As_ = smem + buf * BUFSZ;
        unsigned short* Bs_ = As_ + BM * 64;
        bf16x8 af[FM][2], bfr[FN][2];
#pragma unroll
        for (int mi = 0; mi < FM; mi++) {
            int r = wm*WM + mi*16 + rlo;
#pragma unroll
            for (int s = 0; s < 2; s++)
                af[mi][s] = *(const bf16x8*)(As_ + r*64 + ((s*4 + quad) ^ (r & 7))*8);
        }
#pragma unroll
        for (int ni = 0; ni < FN; ni++) {
            int r = wn*WN + ni*16 + rlo;
#pragma unroll
            for (int s = 0; s < 2; s++)
                bfr[ni][s] = *(const bf16x8*)(Bs_ + r*64 + ((s*4 + quad) ^ (r & 7))*8);
        }
        if (PRIO) __builtin_amdgcn_s_setprio(1);
#pragma unroll
        for (int s = 0; s < 2; s++)
#pragma unroll
            for (int mi = 0; mi < FM; mi++)
#pragma unroll
                for (int ni = 0; ni < FN; ni++)
                    acc[mi][ni] = __builtin_amdgcn_mfma_f32_16x16x32_bf16(
                        af[mi][s], bfr[ni][s], acc[mi][ni], 0, 0, 0);
        if (PRIO) __builtin_amdgcn_s_setprio(0);
    };

    if constexpr (DBUF) {
        stage(0, 0);
        int buf = 0;
        for (int k0 = 0; k0 < Kd; k0 += 64) {
            __syncthreads();                       // drains stage(cur); also fences
            if (k0 + 64 < Kd) stage(buf ^ 1, k0 + 64);   // prefetch next tile
            compute(buf);                          // overlap with prefetch in flight
            buf ^= 1;
        }
    } else {
        for (int k0 = 0; k0 < Kd; k0 += 64) {
            stage(0, k0);
            __syncthreads();                       // staging complete (vmcnt drain)
            compute(0);
            __syncthreads();                       // all reads done before re-stage
        }
    }

    // epilogue: D row = quad*4 + r, col = rlo within each 16x16 tile
#pragma unroll
    for (int mi = 0; mi < FM; mi++) {
#pragma unroll
        for (int ni = 0; ni < FN; ni++) {
            int col = bn0 + wn*WN + ni*16 + rlo;
            float bv = bias[col];
#pragma unroll
            for (int r = 0; r < 4; r++) {
                int row = bm0 + wm*WM + mi*16 + quad*4 + r;
                float val = acc[mi][ni][r] + bv;
                if (EPI == 1) val += res[(size_t)row * N + col];
                if (EPI == 2) {
                    val = gelu_tanh(val);
                    Cb[(size_t)row * N + col] = f2bf(val);
                } else if (EPI == 3) {
                    if (col < DIM_) Cf[(size_t)row * DIM_ + col] = val;
                    else            Cb[(size_t)row * KV_ + (col - DIM_)] = f2bf(val);
                } else {
                    Cf[(size_t)row * N + col] = val;
                }
            }
        }
    }
}

template<int EPI, int BM, int BN>
__global__ __launch_bounds__(256)
void gemm_bf16_kernel(const unsigned short* __restrict__ A,
                      const unsigned short* __restrict__ Bt,
                      const float* __restrict__ bias,
                      const float* __restrict__ res,
                      float* __restrict__ Cf,
                      unsigned short* __restrict__ Cb,
                      int N, int Kd)
{
    __shared__ __align__(16) unsigned short smem[2 * (BM + BN) * 64];
    gemm_block<EPI, BM, BN, true, false>(A, Bt, bias, res, Cf, Cb, N, Kd,
                                         blockIdx.y * BM, blockIdx.x * BN, smem);
}

// ---------------------------------------------------------------------------
// top-K extraction helper (NR regs = NR*64 values per wave partition):
// lt pass (order irrelevant; merge re-ranks) + eq pass in ascending-j order
// (exact jax.lax.top_k lower-index-first).
// ---------------------------------------------------------------------------
template<int NR>
__device__ __forceinline__ void extract_row(const unsigned* rb, unsigned T,
                                            int cnt_lt, int m,
                                            unsigned long long* crow,
                                            int part, int jbase, int lane)
{
    int ltpos = 0;
#pragma unroll
    for (int tt = 0; tt < NR; tt++) {
        bool is_lt = rb[tt] < T;
        unsigned long long mlt = __ballot(is_lt);
        int p = ltpos + lane_mbcnt(mlt);
        if (is_lt) {
            int j = jbase + (tt >> 2)*256 + lane*4 + (tt & 3);
            crow[part*K_ + p] = ((unsigned long long)rb[tt] << 32) | (unsigned)j;
        }
        ltpos += __popcll(mlt);
    }
    int eqpos = 0;
#pragma unroll
    for (int jg = 0; jg < NR/4; jg++) {
        bool iseq[4]; unsigned long long meq[4]; int bel[4];
#pragma unroll
        for (int jj = 0; jj < 4; jj++) {
            iseq[jj] = (rb[jg*4+jj] == T);
            meq[jj]  = __ballot(iseq[jj]);
            bel[jj]  = lane_mbcnt(meq[jj]);
        }
        int lane_prefix = bel[0] + bel[1] + bel[2] + bel[3];
        int within = 0;
#pragma unroll
        for (int jj = 0; jj < 4; jj++) {
            int p = eqpos + lane_prefix + within;
            if (iseq[jj] && p < m) {
                int j = jbase + jg*256 + lane*4 + jj;
                crow[part*K_ + cnt_lt + p] =
                    ((unsigned long long)rb[jg*4+jj] << 32) | (unsigned)j;
            }
            within += iseq[jj] ? 1 : 0;
        }
        eqpos += __popcll(meq[0]) + __popcll(meq[1]) + __popcll(meq[2]) + __popcll(meq[3]);
    }
}

// ---------------------------------------------------------------------------
// Poincare dist + exact top-K block body (R12 structure: 2 rows/block,
// 4 waves = j-quarters, 2-bit radix select with carried counts,
// 128-candidate merge).
// ---------------------------------------------------------------------------
__device__ __forceinline__ void topk_block(const float* __restrict__ pos,
                      const float* __restrict__ posT,
                      const float* __restrict__ pos_sq,
                      const float* __restrict__ c_ptr,
                      int* __restrict__ topk_idx, float* __restrict__ topk_dist,
                      int bi0, unsigned long long (*cand)[128])
{
    int wid  = threadIdx.x >> 6;      // j-quarter 0..3
    int lane = threadIdx.x & 63;
    int b    = bi0 >> 11;             // both rows of a block share the batch
    float c  = *c_ptr;
    float inv_sqrt_c = rsqrtf(c);

    float pi0[16], pi1[16];
    {
        const float4* q0 = (const float4*)(pos + (size_t)bi0 * PD_);
        const float4* q1 = (const float4*)(pos + (size_t)(bi0+1) * PD_);
#pragma unroll
        for (int u = 0; u < 4; u++) {
            float4 a = q0[u];
            pi0[4*u]=a.x; pi0[4*u+1]=a.y; pi0[4*u+2]=a.z; pi0[4*u+3]=a.w;
            float4 e = q1[u];
            pi1[4*u]=e.x; pi1[4*u+1]=e.y; pi1[4*u+2]=e.z; pi1[4*u+3]=e.w;
        }
    }
    float om0 = 1.f - c * pos_sq[bi0];
    float om1 = 1.f - c * pos_sq[bi0+1];

    const float* pT  = posT + (size_t)b * 16 * N_;
    const float* sqb = pos_sq + b * N_;
    int jbase = wid * 512;
    int j0l   = jbase + lane * 4;

    unsigned rb0[8], rb1[8];
#pragma unroll
    for (int jg = 0; jg < 2; jg++) {
        int j0 = j0l + jg * 256;
        float ax=0,ay=0,az=0,aw=0, bx=0,by=0,bz=0,bw=0;
#pragma unroll
        for (int d = 0; d < 16; d++) {
            float4 v = *(const float4*)(pT + d * N_ + j0);
            float d0x = pi0[d]-v.x, d0y = pi0[d]-v.y, d0z = pi0[d]-v.z, d0w = pi0[d]-v.w;
            ax += d0x*d0x; ay += d0y*d0y; az += d0z*d0z; aw += d0w*d0w;
            float d1x = pi1[d]-v.x, d1y = pi1[d]-v.y, d1z = pi1[d]-v.z, d1w = pi1[d]-v.w;
            bx += d1x*d1x; by += d1y*d1y; bz += d1z*d1z; bw += d1w*d1w;
        }
        float4 sq = *(const float4*)(sqb + j0);
        float da[4]={ax,ay,az,aw}, db[4]={bx,by,bz,bw}, sqa[4]={sq.x,sq.y,sq.z,sq.w};
#pragma unroll
        for (int jj = 0; jj < 4; jj++) {
            float omj  = 1.f - c * sqa[jj];
            float den0 = fmaxf(om0 * omj, 1e-8f);
            float den1 = fmaxf(om1 * omj, 1e-8f);
            rb0[jg*4+jj] = __float_as_uint(fmaxf(1.f + 2.f*c*da[jj]/den0, 1.f+1e-7f));
            rb1[jg*4+jj] = __float_as_uint(fmaxf(1.f + 2.f*c*db[jj]/den1, 1.f+1e-7f));
        }
    }

    // --- common-prefix skip + 2-bit radix select, counts carried ---
    unsigned T0, T1;
    int cl0 = 0, cl1 = 0;              // count(< T) — maintained on accept
    {
        unsigned band0 = rb0[0], bor0 = rb0[0], band1 = rb1[0], bor1 = rb1[0];
#pragma unroll
        for (int tt = 1; tt < 8; tt++) {
            band0 &= rb0[tt]; bor0 |= rb0[tt];
            band1 &= rb1[tt]; bor1 |= rb1[tt];
        }
#pragma unroll
        for (int off = 32; off; off >>= 1) {
            band0 &= __shfl_xor(band0, off); bor0 |= __shfl_xor(bor0, off);
            band1 &= __shfl_xor(band1, off); bor1 |= __shfl_xor(bor1, off);
        }
        unsigned df0 = band0 ^ bor0, df1 = band1 ^ bor1;
        int hib0 = df0 ? (31 - __clz(df0)) : -1;
        int hib1 = df1 ? (31 - __clz(df1)) : -1;
        int hib  = hib0 > hib1 ? hib0 : hib1;
        T0 = (hib >= 0) ? (band0 & ~((1u << (hib+1)) - 1u)) : band0;
        T1 = (hib >= 0) ? (band1 & ~((1u << (hib+1)) - 1u)) : band1;
        // count(< T_init) == 0: all values share T's prefix, T's low bits = 0
        int bit = hib;
        while (bit >= 1) {                 // bits (bit, bit-1) per step
            unsigned lo = 1u << (bit - 1);
            unsigned p01 = T0 | lo, p02 = T0 | (lo << 1), p03 = T0 | (lo*3u);
            unsigned p11 = T1 | lo, p12 = T1 | (lo << 1), p13 = T1 | (lo*3u);
            int c01=0,c02=0,c03=0,c11=0,c12=0,c13=0;
#pragma unroll
            for (int tt = 0; tt < 8; tt++) {
                c01 += __popcll(__ballot(rb0[tt] < p01));
                c02 += __popcll(__ballot(rb0[tt] < p02));
                c03 += __popcll(__ballot(rb0[tt] < p03));
                c11 += __popcll(__ballot(rb1[tt] < p11));
                c12 += __popcll(__ballot(rb1[tt] < p12));
                c13 += __popcll(__ballot(rb1[tt] < p13));
            }
            if      (c03 < K_) { T0 = p03; cl0 = c03; }
            else if (c02 < K_) { T0 = p02; cl0 = c02; }
            else if (c01 < K_) { T0 = p01; cl0 = c01; }
            if      (c13 < K_) { T1 = p13; cl1 = c13; }
            else if (c12 < K_) { T1 = p12; cl1 = c12; }
            else if (c11 < K_) { T1 = p11; cl1 = c11; }
            bit -= 2;
        }
        if (bit == 0) {                    // leftover single bit
            unsigned p0 = T0 | 1u, p1 = T1 | 1u;
            int c0 = 0, c1 = 0;
#pragma unroll
            for (int tt = 0; tt < 8; tt++) {
                c0 += __popcll(__ballot(rb0[tt] < p0));
                c1 += __popcll(__ballot(rb1[tt] < p1));
            }
            if (c0 < K_) { T0 = p0; cl0 = c0; }
            if (c1 < K_) { T1 = p1; cl1 = c1; }
        }
    }

    extract_row<8>(rb0, T0, cl0, K_ - cl0, cand[0], wid, jbase, lane);
    extract_row<8>(rb1, T1, cl1, K_ - cl1, cand[1], wid, jbase, lane);
    __syncthreads();

    // --- merge: 2 waves per row rank 128 candidates (4 quarters x K) ---
    {
        int row  = wid >> 1, half = wid & 1;
        unsigned long long mykey = cand[row][half*64 + lane];
        int rank = 0;
#pragma unroll 8
        for (int M = 0; M < 128; M++)
            rank += (cand[row][M] < mykey) ? 1 : 0;
        if (rank < K_) {
            int bi = bi0 + row;
            topk_idx [(size_t)bi * K_ + rank] = (int)(mykey & 0xffffffffu);
            topk_dist[(size_t)bi * K_ + rank] =
                acoshf(__uint_as_float((unsigned)(mykey >> 32))) * inv_sqrt_c;
        }
    }
}

// ---------------------------------------------------------------------------
// FUSED QKV-GEMM + dist/top-K + tail-weight transposes. Grid 5888 = 23*256:
// per group of 23 consecutive blockIdx — 6 GEMM (1536 = 24x64 tiles of
// 64x64) + 8 topk (2048, 2 rows each) + 9 transpose (2304 = Wo 256 /
// W1 1024 / W2 1024 tiles of 32x32). Branch-max VGPR 56, no spills (R17/R20).
// GEMM branch: setprio(1) around MFMA (T5; role diversity from heterogeneous
// co-resident blocks — measured neutral-to-positive R23).
// ---------------------------------------------------------------------------
__global__ __launch_bounds__(256)
void qkv_topk_kernel(const unsigned short* __restrict__ xn,
                     const unsigned short* __restrict__ qkvWt,
                     const float* __restrict__ qkv_b,
                     float* __restrict__ qf,
                     unsigned short* __restrict__ kvb,
                     const float* __restrict__ pos,
                     const float* __restrict__ posT,
                     const float* __restrict__ pos_sq,
                     const float* __restrict__ c_ptr,
                     int* __restrict__ tk_i, float* __restrict__ tk_d,
                     const float* __restrict__ Wo, const float* __restrict__ W1,
                     const float* __restrict__ W2,
                     unsigned short* __restrict__ WoT,
                     unsigned short* __restrict__ W1T,
                     unsigned short* __restrict__ W2T)
{
    __shared__ __align__(16) unsigned short smem[(64 + 64) * 64];  // 16 KB

    int g = blockIdx.x;
    int grp = g / 23;
    int r   = g - grp * 23;
    if (r < 6) {
        int gb = grp * 6 + r;            // [0,1536)
        int bx = gb % 24, by = gb / 24;  // grid 24 x 64 of 64x64 tiles
        gemm_block<3, 64, 64, false, true>(xn, qkvWt, qkv_b, nullptr, qf, kvb,
                                           QKV_, DIM_, by * 64, bx * 64, smem);
    } else if (r < 14) {
        int tb = grp * 8 + (r - 6);      // [0,2048)
        topk_block(pos, posT, pos_sq, c_ptr, tk_i, tk_d, tb * 2,
                   (unsigned long long (*)[128])smem);
    } else {
        int tid = grp * 9 + (r - 14);    // [0,2304)
        const float* W; unsigned short* Wt; int Kd, Nw, nx, ti;
        if      (tid < 256)  { W = Wo; Wt = WoT; Kd = 512;  Nw = 512;  nx = 16; ti = tid; }
        else if (tid < 1280) { W = W1; Wt = W1T; Kd = 512;  Nw = 2048; nx = 64; ti = tid - 256; }
        else                 { W = W2; Wt = W2T; Kd = 2048; Nw = 512;  nx = 16; ti = tid - 1280; }
        float (*tile)[33] = (float (*)[33])smem;   // 32x33 f32 = 4224B < 16KB
        int t  = threadIdx.x;
        int n0 = (ti % nx) * 32, k0 = (ti / nx) * 32;
        int tx = t & 31, ty = t >> 5;
#pragma unroll
        for (int i = 0; i < 32; i += 8)
            tile[ty + i][tx] = W[(size_t)(k0 + ty + i) * Nw + n0 + tx];
        __syncthreads();
#pragma unroll
        for (int i = 0; i < 32; i += 8)
            Wt[(size_t)(n0 + ty + i) * Kd + k0 + tx] = f2bf(tile[tx][ty + i]);
    }
}

// ---------------------------------------------------------------------------
// FUSED prep (critical-path only): Wq/Wk/Wv transposes + bias3 pack +
// pos_sq/posT + LN1 (vectorized). (Wo/W1/W2 transposes live in
// qkv_topk_kernel since R20.)
// id: [0,768) qkv transposes ; [768,774) bias ; [774,790) pos ; [790,1814) LN1
// ---------------------------------------------------------------------------
__global__ void fused_prep_kernel(const float* __restrict__ Wq, const float* __restrict__ Wk,
                            const float* __restrict__ Wv,
                            const float* __restrict__ bq, const float* __restrict__ bk,
                            const float* __restrict__ bv,
                            unsigned short* __restrict__ qkvWt,
                            float* __restrict__ qkv_b,
                            const float* __restrict__ pos,
                            float* __restrict__ pos_sq,
                            float* __restrict__ posT,
                            const float* __restrict__ x,
                            const float* __restrict__ ln1_scale,
                            const float* __restrict__ ln1_bias,
                            unsigned short* __restrict__ xn)
{
    int id = blockIdx.x;
    int t  = threadIdx.x;

    if (id >= 790) {                  // LN1 (vectorized)
        int wave = (id - 790) * 4 + (t >> 6);
        int lane = t & 63;
        ln_row_vec(x + (size_t)wave * DIM_, ln1_scale, ln1_bias,
                   xn + (size_t)wave * DIM_, lane);
        return;
    }
    if (id >= 774) {                  // pos_sq + posT
        int i = (id - 774) * 256 + t;
        int b = i >> 11, j = i & (N_ - 1);
        const float4* p = (const float4*)(pos + (size_t)i * PD_);
        float4 a0 = p[0], a1 = p[1], a2 = p[2], a3 = p[3];
        float pv[16] = {a0.x,a0.y,a0.z,a0.w, a1.x,a1.y,a1.z,a1.w,
                        a2.x,a2.y,a2.z,a2.w, a3.x,a3.y,a3.z,a3.w};
        float s = 0.f;
#pragma unroll
        for (int d = 0; d < 16; d++) s += pv[d]*pv[d];
        pos_sq[i] = s;
        float* pT = posT + (size_t)b * 16 * N_;
#pragma unroll
        for (int d = 0; d < 16; d++) pT[d * N_ + j] = pv[d];
        return;
    }
    if (id >= 768) {                  // bias pack
        int i = (id - 768) * 256 + t;
        if (i < DIM_)            qkv_b[i] = bq[i];
        else if (i < 2*DIM_)     qkv_b[i] = bk[i - DIM_];
        else                     qkv_b[i] = bv[i - 2*DIM_];
        return;
    }

    const float* W; unsigned short* Wt; int ti;
    if      (id < 256)  { W = Wq; Wt = qkvWt;             ti = id; }
    else if (id < 512)  { W = Wk; Wt = qkvWt + 512*512;   ti = id - 256; }
    else                { W = Wv; Wt = qkvWt + 2*512*512; ti = id - 512; }

    __shared__ float tile[32][33];
    int n0 = (ti % 16) * 32, k0 = (ti / 16) * 32;
    int tx = t & 31, ty = t >> 5;
#pragma unroll
    for (int i = 0; i < 32; i += 8)
        tile[ty + i][tx] = W[(size_t)(k0 + ty + i) * 512 + n0 + tx];
    __syncthreads();
#pragma unroll
    for (int i = 0; i < 32; i += 8)
        Wt[(size_t)(n0 + ty + i) * 512 + k0 + tx] = f2bf(tile[tx][ty + i]);
}

// ---------------------------------------------------------------------------
// LayerNorm standalone (LN2) — vectorized
// ---------------------------------------------------------------------------
__global__ void layernorm_kernel(const float* __restrict__ x,
                                 const float* __restrict__ scale,
                                 const float* __restrict__ bias,
                                 unsigned short* __restrict__ y)
{
    int wave = (blockIdx.x * blockDim.x + threadIdx.x) >> 6;
    int lane = threadIdx.x & 63;
    if (wave >= TOK_) return;
    ln_row_vec(x + (size_t)wave * DIM_, scale, bias,
               y + (size_t)wave * DIM_, lane);
}

// ---------------------------------------------------------------------------
// Sparse attention with bf16 K/V. One wave per (b,h,i).
// ---------------------------------------------------------------------------
__global__ __launch_bounds__(256)
void attn_kernel(const float* __restrict__ q,
                 const unsigned short* __restrict__ kv,
                 const int* __restrict__ topk_idx, const float* __restrict__ topk_dist,
                 const float* __restrict__ log_tau_p, const float* __restrict__ attn_scale_p,
                 unsigned int* __restrict__ out)   // bf16 pairs
{
    int gw   = (blockIdx.x * blockDim.x + threadIdx.x) >> 6;
    int lane = threadIdx.x & 63;
    if (gw >= B_ * NH_ * N_) return;
    int b = gw / (NH_ * N_);
    int r = gw % (NH_ * N_);
    int h = r / N_;
    int i = r % N_;
    int tok = b * N_ + i;

    float tau    = fmaxf(__expf(*log_tau_p), 1e-8f);
    float ascale = *attn_scale_p;

    const int*   idxp = topk_idx  + (size_t)tok * K_;
    const float* dstp = topk_dist + (size_t)tok * K_;
    int   my_idx  = idxp[lane & 31];
    float my_dist = dstp[lane & 31];

    int jj   = lane >> 1;
    int half = lane & 1;

    // q half: 32 floats
    const float4* qp = (const float4*)(q + (size_t)tok * DIM_ + h * HD_ + half * 32);
    float4 qv[8];
#pragma unroll
    for (int u = 0; u < 8; u++) qv[u] = qp[u];

    // k half (bf16): 32 shorts = 4 x 16B
    int nb = __shfl(my_idx, jj);
    const uint4* kp = (const uint4*)(kv + (size_t)(b * N_ + nb) * KV_ + h * HD_ + half * 32);
    float dot = 0.f;
#pragma unroll
    for (int u = 0; u < 4; u++) {
        uint4 kw = kp[u];
        dot += qv[2*u].x   * bflo(kw.x) + qv[2*u].y   * bfhi(kw.x)
             + qv[2*u].z   * bflo(kw.y) + qv[2*u].w   * bfhi(kw.y)
             + qv[2*u+1].x * bflo(kw.z) + qv[2*u+1].y * bfhi(kw.z)
             + qv[2*u+1].z * bflo(kw.w) + qv[2*u+1].w * bfhi(kw.w);
    }
    dot += __shfl_xor(dot, 1);   // full dot on both lanes of the pair

    float fs = dot * 0.125f;                        // 1/sqrt(64)
    float gs = -__shfl(my_dist, jj) / tau;
    float s  = ascale * tanh_fast(fs + gs);

    // softmax over the 32 scores (each duplicated on a lane pair)
    float mx = s;
#pragma unroll
    for (int off = 32; off; off >>= 1) mx = fmaxf(mx, __shfl_xor(mx, off));
    float e  = __expf(s - mx);
    float ec = half ? 0.f : e;
#pragma unroll
    for (int off = 32; off; off >>= 1) ec += __shfl_xor(ec, off);
    float inv = 1.f / ec;

    // V phase: dim pair d2 = 2*(lane&31); lane>=32 handles odd neighbors
    int dp    = lane & 31;
    int half2 = lane >> 5;
    const unsigned int* vb = (const unsigned int*)(kv + DIM_ + h * HD_) + dp;
    float ax = 0.f, ay = 0.f;
#pragma unroll
    for (int it = 0; it < 16; it++) {
        int t2 = half2 + 2*it;
        float w  = __shfl(e, t2 * 2) * inv;
        int   nj = __shfl(my_idx, t2);
        unsigned vv = vb[(size_t)(b * N_ + nj) * (KV_/2)];
        ax += w * bflo(vv);
        ay += w * bfhi(vv);
    }
    ax += __shfl_xor(ax, 32);
    ay += __shfl_xor(ay, 32);
    if (lane < 32) {
        unsigned pck = ((unsigned)f2bf(ay) << 16) | (unsigned)f2bf(ax);
        out[(size_t)tok * (DIM_/2) + h * (HD_/2) + dp] = pck;
    }
}

// ---------------------------------------------------------------------------
extern "C" void kernel_launch(void* const* d_in, const int* in_sizes, int n_in,
                              void* d_out, int out_size, void* d_ws, size_t ws_size,
                              hipStream_t stream)
{
    const float* x          = (const float*)d_in[0];
    const float* positions  = (const float*)d_in[1];
    const float* c_p        = (const float*)d_in[2];
    const float* Wq         = (const float*)d_in[3];
    const float* bq         = (const float*)d_in[4];
    const float* Wk         = (const float*)d_in[5];
    const float* bk         = (const float*)d_in[6];
    const float* Wv         = (const float*)d_in[7];
    const float* bv         = (const float*)d_in[8];
    const float* Wo         = (const float*)d_in[9];
    const float* bo         = (const float*)d_in[10];
    const float* W1         = (const float*)d_in[11];
    const float* b1         = (const float*)d_in[12];
    const float* W2         = (const float*)d_in[13];
    const float* b2         = (const float*)d_in[14];
    const float* ln1_scale  = (const float*)d_in[15];
    const float* ln1_bias   = (const float*)d_in[16];
    const float* ln2_scale  = (const float*)d_in[17];
    const float* ln2_bias   = (const float*)d_in[18];
    const float* log_tau    = (const float*)d_in[19];
    const float* attn_scale = (const float*)d_in[20];

    char* p = (char*)d_ws;
    unsigned short* qkvWt  = (unsigned short*)p; p += (size_t)QKV_ * DIM_ * 2;   // [1536][512] bf16
    unsigned short* WoT    = (unsigned short*)p; p += (size_t)DIM_ * DIM_ * 2;   // [512][512]
    unsigned short* W1T    = (unsigned short*)p; p += (size_t)FFN_ * DIM_ * 2;   // [2048][512]
    unsigned short* W2T    = (unsigned short*)p; p += (size_t)DIM_ * FFN_ * 2;   // [512][2048]
    float*          qkv_b  = (float*)p;          p += (size_t)QKV_ * 4;
    unsigned short* xn     = (unsigned short*)p; p += (size_t)TOK_ * DIM_ * 2;   // bf16
    float*          qf     = (float*)p;          p += (size_t)TOK_ * DIM_ * 4;   // fp32 q
    unsigned short* kvb    = (unsigned short*)p; p += (size_t)TOK_ * KV_ * 2;    // bf16 k|v
    unsigned short* attn_o = (unsigned short*)p; p += (size_t)TOK_ * DIM_ * 2;   // bf16
    float*          x1     = (float*)p;          p += (size_t)TOK_ * DIM_ * 4;
    unsigned short* x2n    = (unsigned short*)p; p += (size_t)TOK_ * DIM_ * 2;
    unsigned short* hbuf   = (unsigned short*)p; p += (size_t)TOK_ * FFN_ * 2;
    float*          pos_sq = (float*)p;          p += (size_t)TOK_ * 4;
    float*          posT   = (float*)p;          p += (size_t)B_ * 16 * N_ * 4;
    float*          tk_d   = (float*)p;          p += (size_t)TOK_ * K_ * 4;
    int*            tk_i   = (int*)p;            p += (size_t)TOK_ * K_ * 4;

    // --- prep (critical path only): qkv transposes + bias + pos + LN1 ---
    fused_prep_kernel<<<1814, 256, 0, stream>>>(Wq, Wk, Wv, bq, bk, bv,
                                                qkvWt, qkv_b,
                                                positions, pos_sq, posT,
                                                x, ln1_scale, ln1_bias, xn);

    // --- FUSED: QKV GEMM (1536) + dist/top-k (2048) + Wo/W1/W2 transposes
    //     (2304), 6:8:9 interleave over 5888 = 23*256 blocks ---
    qkv_topk_kernel<<<5888, 256, 0, stream>>>(xn, qkvWt, qkv_b, qf, kvb,
                                              positions, posT, pos_sq, c_p,
                                              tk_i, tk_d,
                                              Wo, W1, W2, WoT, W1T, W2T);

    // --- sparse attention -> bf16 ---
    attn_kernel<<<(B_*NH_*N_)/4, 256, 0, stream>>>(qf, kvb, tk_i, tk_d,
                                                   log_tau, attn_scale,
                                                   (unsigned int*)attn_o);

    // --- x1 = x + attn_o @ Wo + bo (fp32), 64x64 -> 512 blocks, dbuf ---
    gemm_bf16_kernel<1,64,64><<<dim3(DIM_/64, TOK_/64), 256, 0, stream>>>(
        attn_o, WoT, bo, x, x1, nullptr, DIM_, DIM_);

    // --- LN2 -> bf16 (vectorized) ---
    layernorm_kernel<<<TOK_/4, 256, 0, stream>>>(x1, ln2_scale, ln2_bias, x2n);

    // --- FFN1: gelu(x2n @ W1 + b1) -> bf16 h, 128x128 -> 512 blocks, dbuf ---
    gemm_bf16_kernel<2,128,128><<<dim3(FFN_/128, TOK_/128), 256, 0, stream>>>(
        x2n, W1T, b1, nullptr, nullptr, hbuf, FFN_, DIM_);

    // --- FFN2: out = x1 + h @ W2 + b2 (fp32), 64x64 -> 512 blocks, dbuf
    //     (R24: reverted from 64x128 — 256 blocks = 1 block/CU exposed dbuf
    //      staging latency with only 1 wave/SIMD; 512 blocks at 64x64 wins
    //      at this grid size despite lower per-FLOP tile efficiency) ---
    gemm_bf16_kernel<1,64,64><<<dim3(DIM_/64, TOK_/64), 256, 0, stream>>>(
        hbuf, W2T, b2, x1, (float*)d_out, nullptr, DIM_, FFN_);
}